// Round 1
// baseline (255.737 us; speedup 1.0000x reference)
//
#include <hip/hip_runtime.h>

#define IMG_H 192
#define IMG_W 192
#define NG    1024
#define FRONT_K 8
#define ALPHA_THRESH (1.0f / 255.0f)
#define ALPHA_CLAMP  0.999f

// ---------------------------------------------------------------------------
// Kernel 1: depth sort (stable via index tie-break) of 1024 gaussians.
// One block, 1024 threads, in-LDS bitonic sort. Writes sorted order to ws.
// ---------------------------------------------------------------------------
__global__ __launch_bounds__(NG) void sort_depths(
    const float* __restrict__ depths, int* __restrict__ order_out)
{
    __shared__ float sd[NG];
    __shared__ int   si[NG];
    const int t = threadIdx.x;
    sd[t] = depths[t];
    si[t] = t;
    __syncthreads();

    for (int k = 2; k <= NG; k <<= 1) {
        for (int j = k >> 1; j > 0; j >>= 1) {
            const int ixj = t ^ j;
            if (ixj > t) {
                const float d1 = sd[t],  d2 = sd[ixj];
                const int   i1 = si[t],  i2 = si[ixj];
                const bool up = ((t & k) == 0);
                // strict total order (depth, index) -> stable-argsort-equal
                const bool gt = (d1 > d2) || (d1 == d2 && i1 > i2);
                if (up == gt) {
                    sd[t] = d2; sd[ixj] = d1;
                    si[t] = i2; si[ixj] = i1;
                }
            }
            __syncthreads();
        }
    }
    order_out[t] = si[t];
}

// ---------------------------------------------------------------------------
// Kernel 2: rasterize. 1 thread = 1 pixel. Each block stages all sorted
// gaussian data into LDS (gathered through the sorted order), then each
// lane walks front-to-back with the first-K-valid truncation.
// LDS layout per gaussian:
//   lA = (mean_x, mean_y, conic_a, conic_b)
//   lB = (conic_c, sigma_threshold = ln(255*op)+margin)
//   lC = (opacity, col_r, col_g, col_b)
// ---------------------------------------------------------------------------
__global__ __launch_bounds__(256) void raster(
    const int*   __restrict__ order,
    const float* __restrict__ means2d,
    const float* __restrict__ conics,
    const float* __restrict__ colors,
    const float* __restrict__ opac,
    float*       __restrict__ out)
{
    __shared__ float4 lA[NG];
    __shared__ float2 lB[NG];
    __shared__ float4 lC[NG];

    const int tid = threadIdx.x;
    for (int i = tid; i < NG; i += 256) {
        const int o = order[i];
        const float mx = means2d[o * 2 + 0];
        const float my = means2d[o * 2 + 1];
        const float ca = conics[o * 3 + 0];
        const float cb = conics[o * 3 + 1];
        const float cc = conics[o * 3 + 2];
        const float op = opac[o];
        lA[i] = make_float4(mx, my, ca, cb);
        // conservative pre-filter threshold: if sigma > ln(255*op)+1e-3 the
        // exact test op*exp(-sigma) >= 1/255 cannot pass (margin >> ulps).
        lB[i] = make_float2(cc, __logf(255.0f * op) + 1e-3f);
        lC[i] = make_float4(op, colors[o * 3 + 0], colors[o * 3 + 1],
                            colors[o * 3 + 2]);
    }
    __syncthreads();

    const int pix = blockIdx.x * 256 + tid;
    const float px = (float)(pix % IMG_W) + 0.5f;
    const float py = (float)(pix / IMG_W) + 0.5f;

    float T = 1.0f;
    float accr = 0.0f, accg = 0.0f, accb = 0.0f;
    int cnt = 0;

    for (int g = 0; g < NG; ++g) {
        const float4 A  = lA[g];
        const float2 Bv = lB[g];
        const float dx = px - A.x;
        const float dy = py - A.y;
        // same op order as reference: 0.5*(a*dx^2 + c*dy^2) + b*dx*dy
        const float sigma = 0.5f * (A.z * dx * dx + Bv.x * dy * dy)
                          + A.w * dx * dy;
        if (sigma >= 0.0f && sigma <= Bv.y && cnt < FRONT_K) {
            const float4 C = lC[g];
            float alpha = C.x * __expf(-sigma);
            if (alpha >= ALPHA_THRESH) {          // exact reference test
                alpha = fminf(alpha, ALPHA_CLAMP);
                const float w = T * alpha;
                accr += w * C.y;
                accg += w * C.z;
                accb += w * C.w;
                T *= (1.0f - alpha);
                ++cnt;
            }
        }
        if ((g & 63) == 63 && __all(cnt >= FRONT_K)) break;
    }

    // BG is (0,0,0): no background term.
    out[pix * 3 + 0] = accr;
    out[pix * 3 + 1] = accg;
    out[pix * 3 + 2] = accb;
}

// ---------------------------------------------------------------------------
extern "C" void kernel_launch(void* const* d_in, const int* in_sizes, int n_in,
                              void* d_out, int out_size, void* d_ws, size_t ws_size,
                              hipStream_t stream)
{
    const float* means2d = (const float*)d_in[0];   // [1,1024,2]
    const float* conics  = (const float*)d_in[1];   // [1,1024,3]
    const float* colors  = (const float*)d_in[2];   // [1,1024,3]
    const float* opac    = (const float*)d_in[3];   // [1,1024]
    const float* depths  = (const float*)d_in[4];   // [1,1024]

    int* order = (int*)d_ws;                         // 4 KB of scratch

    sort_depths<<<1, NG, 0, stream>>>(depths, order);
    raster<<<(IMG_H * IMG_W) / 256, 256, 0, stream>>>(
        order, means2d, conics, colors, opac, (float*)d_out);
}

// Round 3
// 115.475 us; speedup vs baseline: 2.2147x; 2.2147x over previous
//
#include <hip/hip_runtime.h>

#define IMG_H 192
#define IMG_W 192
#define NG    1024
#define TILE  8            // 8x8 pixel tiles
#define TX    24           // IMG_W / TILE
#define TY    24           // IMG_H / TILE
#define FRONT_K 8
#define ALPHA_THRESH (1.0f / 255.0f)
#define ALPHA_CLAMP  0.999f

// Workspace: gaussian data scattered into depth-sorted order by the setup
// kernel. 44 KB total.
struct WS {
    float4 A4[NG];     // mx, my, conic_a, conic_b
    float4 B4[NG];     // conic_c, sigma_thr, opacity, col_r
    float2 C2[NG];     // col_g, col_b
    unsigned int range[NG];  // packed tile bbox: tx0 | ty0<<8 | tx1<<16 | ty1<<24
};

// ---------------------------------------------------------------------------
// Kernel 1: fused rank-sort (O(N^2), replaces 55-stage bitonic) + bbox
// precompute + scatter into sorted order. 16 blocks x 64 threads = 1024.
// rank_i = #{ j : d_j < d_i  or (d_j == d_i and j < i) }  -> exact stable
// argsort permutation (matches jnp.argsort).
// ---------------------------------------------------------------------------
__global__ __launch_bounds__(64) void setup(
    const float* __restrict__ means2d, const float* __restrict__ conics,
    const float* __restrict__ colors,  const float* __restrict__ opac,
    const float* __restrict__ depths,  WS* __restrict__ ws)
{
    const int g = blockIdx.x * 64 + threadIdx.x;
    const float dg = depths[g];

    // rank via 256 uniform float4 loads (wave-uniform address -> broadcast)
    int rank = 0;
    const float4* d4 = (const float4*)depths;
    for (int j4 = 0; j4 < NG / 4; ++j4) {
        const float4 v = d4[j4];
        const int j = j4 * 4;
        rank += (v.x < dg || (v.x == dg && (j + 0) < g));
        rank += (v.y < dg || (v.y == dg && (j + 1) < g));
        rank += (v.z < dg || (v.z == dg && (j + 2) < g));
        rank += (v.w < dg || (v.w == dg && (j + 3) < g));
    }

    const float mx = means2d[2 * g + 0];
    const float my = means2d[2 * g + 1];
    const float ca = conics[3 * g + 0];
    const float cb = conics[3 * g + 1];
    const float cc = conics[3 * g + 2];
    const float op = opac[g];

    // exact alpha test passes only if sigma <= ln(255*op); +1e-3 margin
    // (>> f32 ulps) keeps the pre-filter conservative.
    const float thr = __logf(255.0f * op) + 1e-3f;

    // conservative ellipse bbox: dx^2 <= 2*thr*c/det, dy^2 <= 2*thr*a/det
    const float det = ca * cc - cb * cb;
    unsigned int pr = 0x000000FFu;  // empty marker: tx0=255 > any tx
    if (thr > 0.0f && det > 0.0f) {
        const float hx = sqrtf(2.0f * thr * cc / det) + 0.01f;
        const float hy = sqrtf(2.0f * thr * ca / det) + 0.01f;
        // pixel centers px = x + 0.5 : need |px - mx| <= hx
        const int x0 = max(0, (int)ceilf(mx - hx - 0.5f));
        const int x1 = min(IMG_W - 1, (int)floorf(mx + hx - 0.5f));
        const int y0 = max(0, (int)ceilf(my - hy - 0.5f));
        const int y1 = min(IMG_H - 1, (int)floorf(my + hy - 0.5f));
        if (x0 <= x1 && y0 <= y1) {
            const unsigned int tx0 = x0 >> 3, tx1 = x1 >> 3;
            const unsigned int ty0 = y0 >> 3, ty1 = y1 >> 3;
            pr = tx0 | (ty0 << 8) | (tx1 << 16) | (ty1 << 24);
        }
    }

    ws->A4[rank] = make_float4(mx, my, ca, cb);
    ws->B4[rank] = make_float4(cc, thr, op, colors[3 * g + 0]);
    ws->C2[rank] = make_float2(colors[3 * g + 1], colors[3 * g + 2]);
    ws->range[rank] = pr;
}

// ---------------------------------------------------------------------------
// Kernel 2: rasterize. 1 block = 1 wave = one 8x8 pixel tile (576 blocks).
// Phase 1: ballot-compaction of the depth-sorted gaussian list against this
//          tile's coords (order-preserving, wave-synchronous, no barriers).
// Phase 2: front-to-back composite over the (short) tile list with the exact
//          reference validity test and first-K truncation.
// ---------------------------------------------------------------------------
__global__ __launch_bounds__(64) void raster(
    const WS* __restrict__ ws, float* __restrict__ out)
{
    __shared__ unsigned short slist[NG];

    const int lane = threadIdx.x;
    const int tx = blockIdx.x % TX;
    const int ty = blockIdx.x / TX;

    // --- phase 1: order-preserving compaction ---
    int base = 0;
    for (int c = 0; c < NG / 64; ++c) {
        const int g = c * 64 + lane;
        const unsigned int pr = ws->range[g];        // coalesced
        const int x0 = pr & 0xFF, y0 = (pr >> 8) & 0xFF;
        const int x1 = (pr >> 16) & 0xFF, y1 = (pr >> 24) & 0xFF;
        const bool hit = (x0 <= tx) & (tx <= x1) & (y0 <= ty) & (ty <= y1);
        const unsigned long long m = __ballot(hit);
        if (hit) {
            const int pos = base +
                __popcll(m & ((1ull << lane) - 1ull));
            slist[pos] = (unsigned short)g;
        }
        base += __popcll(m);
    }
    __syncthreads();   // 1-wave block: near-free; removes DS-ordering assumption

    // --- phase 2: composite ---
    const int col = lane & 7, row = lane >> 3;
    const float px = (float)(tx * TILE + col) + 0.5f;
    const float py = (float)(ty * TILE + row) + 0.5f;

    float T = 1.0f, accr = 0.0f, accg = 0.0f, accb = 0.0f;
    int cnt = 0;

    for (int i = 0; i < base; ++i) {
        // all lanes read the same entry -> hoist to SGPR, loads become s_load
        const int g = __builtin_amdgcn_readfirstlane((int)slist[i]);
        const float4 A  = ws->A4[g];
        const float4 Bv = ws->B4[g];
        const float dx = px - A.x;
        const float dy = py - A.y;
        // same op order as reference
        const float sigma = 0.5f * (A.z * dx * dx + Bv.x * dy * dy)
                          + A.w * dx * dy;
        if (sigma >= 0.0f && sigma <= Bv.y && cnt < FRONT_K) {
            float alpha = Bv.z * __expf(-sigma);
            if (alpha >= ALPHA_THRESH) {            // exact reference test
                alpha = fminf(alpha, ALPHA_CLAMP);
                const float w = T * alpha;
                const float2 C = ws->C2[g];
                accr += w * Bv.w;
                accg += w * C.x;
                accb += w * C.y;
                T *= (1.0f - alpha);
                ++cnt;
            }
        }
        if ((i & 7) == 7 && __all(cnt >= FRONT_K)) break;
    }

    // BG = (0,0,0): no background term.
    const int pix = (ty * TILE + row) * IMG_W + (tx * TILE + col);
    out[pix * 3 + 0] = accr;
    out[pix * 3 + 1] = accg;
    out[pix * 3 + 2] = accb;
}

// ---------------------------------------------------------------------------
extern "C" void kernel_launch(void* const* d_in, const int* in_sizes, int n_in,
                              void* d_out, int out_size, void* d_ws, size_t ws_size,
                              hipStream_t stream)
{
    const float* means2d = (const float*)d_in[0];   // [1,1024,2]
    const float* conics  = (const float*)d_in[1];   // [1,1024,3]
    const float* colors  = (const float*)d_in[2];   // [1,1024,3]
    const float* opac    = (const float*)d_in[3];   // [1,1024]
    const float* depths  = (const float*)d_in[4];   // [1,1024]

    WS* ws = (WS*)d_ws;  // 44 KB

    setup<<<NG / 64, 64, 0, stream>>>(means2d, conics, colors, opac, depths, ws);
    raster<<<TX * TY, 64, 0, stream>>>(ws, (float*)d_out);
}

// Round 8
// 101.545 us; speedup vs baseline: 2.5185x; 1.1372x over previous
//
#include <hip/hip_runtime.h>

#define IMG_H 192
#define IMG_W 192
#define NG    1024
#define TILE  8            // 8x8 pixel tiles
#define TX    24           // IMG_W / TILE
#define TY    24           // IMG_H / TILE
#define FRONT_K 8
#define ALPHA_THRESH (1.0f / 255.0f)
#define ALPHA_CLAMP  0.999f
#define CAP   64           // candidates staged to LDS per chunk

// Workspace: gaussian data scattered into depth-sorted order by setup. 44 KB.
struct WS {
    float4 A4[NG];     // mx, my, conic_a, conic_b
    float4 B4[NG];     // conic_c, sigma_thr, opacity, col_r
    float2 C2[NG];     // col_g, col_b
    unsigned int range[NG];  // packed tile bbox: tx0 | ty0<<8 | tx1<<16 | ty1<<24
};

// ---------------------------------------------------------------------------
// Kernel 1: fused rank-sort + bbox + scatter. 16 blocks x 64 threads.
// v2: depths staged in LDS; rank loop unrolled 8x -> 8 ds_read_b128 in
// flight (wave-uniform = broadcast) instead of 256 serial L2-latency loads.
// rank_i = #{ j : d_j < d_i or (d_j == d_i and j < i) } -> exact stable
// argsort permutation (matches jnp.argsort).
// ---------------------------------------------------------------------------
__global__ __launch_bounds__(64) void setup(
    const float* __restrict__ means2d, const float* __restrict__ conics,
    const float* __restrict__ colors,  const float* __restrict__ opac,
    const float* __restrict__ depths,  WS* __restrict__ ws)
{
    __shared__ float sdep[NG];
    const int lane = threadIdx.x;

    // stage all 1024 depths: 4 coalesced float4 loads per lane
    const float4* d4 = (const float4*)depths;
    float4* s4 = (float4*)sdep;
    #pragma unroll
    for (int i = 0; i < NG / 4 / 64; ++i)
        s4[i * 64 + lane] = d4[i * 64 + lane];
    __syncthreads();

    const int g = blockIdx.x * 64 + lane;
    const float dg = sdep[g];

    int rank = 0;
    const float4* sv = (const float4*)sdep;
    #pragma unroll 8
    for (int j4 = 0; j4 < NG / 4; ++j4) {
        const float4 v = sv[j4];               // wave-uniform -> broadcast
        const int j = j4 * 4;
        rank += (v.x < dg || (v.x == dg && (j + 0) < g));
        rank += (v.y < dg || (v.y == dg && (j + 1) < g));
        rank += (v.z < dg || (v.z == dg && (j + 2) < g));
        rank += (v.w < dg || (v.w == dg && (j + 3) < g));
    }

    const float mx = means2d[2 * g + 0];
    const float my = means2d[2 * g + 1];
    const float ca = conics[3 * g + 0];
    const float cb = conics[3 * g + 1];
    const float cc = conics[3 * g + 2];
    const float op = opac[g];

    // exact alpha test passes only if sigma <= ln(255*op); +1e-3 margin
    // (>> f32 ulps) keeps the pre-filter conservative.
    const float thr = __logf(255.0f * op) + 1e-3f;

    // conservative ellipse bbox: dx^2 <= 2*thr*c/det, dy^2 <= 2*thr*a/det
    const float det = ca * cc - cb * cb;
    unsigned int pr = 0x000000FFu;  // empty marker: tx0=255 > any tx
    if (thr > 0.0f && det > 0.0f) {
        const float hx = sqrtf(2.0f * thr * cc / det) + 0.01f;
        const float hy = sqrtf(2.0f * thr * ca / det) + 0.01f;
        const int x0 = max(0, (int)ceilf(mx - hx - 0.5f));
        const int x1 = min(IMG_W - 1, (int)floorf(mx + hx - 0.5f));
        const int y0 = max(0, (int)ceilf(my - hy - 0.5f));
        const int y1 = min(IMG_H - 1, (int)floorf(my + hy - 0.5f));
        if (x0 <= x1 && y0 <= y1) {
            const unsigned int tx0 = x0 >> 3, tx1 = x1 >> 3;
            const unsigned int ty0 = y0 >> 3, ty1 = y1 >> 3;
            pr = tx0 | (ty0 << 8) | (tx1 << 16) | (ty1 << 24);
        }
    }

    ws->A4[rank] = make_float4(mx, my, ca, cb);
    ws->B4[rank] = make_float4(cc, thr, op, colors[3 * g + 0]);
    ws->C2[rank] = make_float2(colors[3 * g + 1], colors[3 * g + 2]);
    ws->range[rank] = pr;
}

// ---------------------------------------------------------------------------
// Kernel 2: rasterize. 1 block = 1 wave = one 8x8 tile (576 blocks).
// v2: (a) all 16 range chunks loaded to registers up-front (one waitcnt),
//     (b) candidate gaussian data gathered chunk-wise into LDS in parallel
//         (1 lane = 1 candidate) -> composite loop reads LDS broadcasts
//         instead of serial global-latency loads.
// ---------------------------------------------------------------------------
__global__ __launch_bounds__(64) void raster(
    const WS* __restrict__ ws, float* __restrict__ out)
{
    __shared__ unsigned short slist[NG];
    __shared__ float4 gA[CAP];
    __shared__ float4 gB[CAP];
    __shared__ float2 gC[CAP];

    const int lane = threadIdx.x;
    const int tx = blockIdx.x % TX;
    const int ty = blockIdx.x / TX;

    // --- phase 1: order-preserving compaction ---
    unsigned int prs[NG / 64];
    #pragma unroll
    for (int c = 0; c < NG / 64; ++c)            // 16 coalesced loads in flight
        prs[c] = ws->range[c * 64 + lane];

    int base = 0;
    #pragma unroll
    for (int c = 0; c < NG / 64; ++c) {
        const unsigned int pr = prs[c];
        const int x0 = pr & 0xFF, y0 = (pr >> 8) & 0xFF;
        const int x1 = (pr >> 16) & 0xFF, y1 = (pr >> 24) & 0xFF;
        const bool hit = (x0 <= tx) & (tx <= x1) & (y0 <= ty) & (ty <= y1);
        const unsigned long long m = __ballot(hit);
        if (hit) {
            const int pos = base + __popcll(m & ((1ull << lane) - 1ull));
            slist[pos] = (unsigned short)(c * 64 + lane);
        }
        base += __popcll(m);
    }
    __syncthreads();

    // --- phase 2: chunked LDS gather + composite ---
    const int col = lane & 7, row = lane >> 3;
    const float px = (float)(tx * TILE + col) + 0.5f;
    const float py = (float)(ty * TILE + row) + 0.5f;

    float T = 1.0f, accr = 0.0f, accg = 0.0f, accb = 0.0f;
    int cnt = 0;

    for (int start = 0; start < base; start += CAP) {
        const int n = min(CAP, base - start);
        if (lane < n) {                           // parallel gather, 1 latency
            const int g = slist[start + lane];
            gA[lane] = ws->A4[g];
            gB[lane] = ws->B4[g];
            gC[lane] = ws->C2[g];
        }
        __syncthreads();

        for (int i = 0; i < n; ++i) {
            const float4 A  = gA[i];              // wave-uniform broadcast
            const float4 Bv = gB[i];
            const float dx = px - A.x;
            const float dy = py - A.y;
            // same op order as reference
            const float sigma = 0.5f * (A.z * dx * dx + Bv.x * dy * dy)
                              + A.w * dx * dy;
            if (sigma >= 0.0f && sigma <= Bv.y && cnt < FRONT_K) {
                float alpha = Bv.z * __expf(-sigma);
                if (alpha >= ALPHA_THRESH) {      // exact reference test
                    alpha = fminf(alpha, ALPHA_CLAMP);
                    const float w = T * alpha;
                    const float2 C = gC[i];
                    accr += w * Bv.w;
                    accg += w * C.x;
                    accb += w * C.y;
                    T *= (1.0f - alpha);
                    ++cnt;
                }
            }
            if ((i & 7) == 7 && __all(cnt >= FRONT_K)) { start = NG; break; }
        }
        __syncthreads();                          // before next chunk rewrite
        if (__all(cnt >= FRONT_K)) break;
    }

    // BG = (0,0,0): no background term.
    const int pix = (ty * TILE + row) * IMG_W + (tx * TILE + col);
    out[pix * 3 + 0] = accr;
    out[pix * 3 + 1] = accg;
    out[pix * 3 + 2] = accb;
}

// ---------------------------------------------------------------------------
extern "C" void kernel_launch(void* const* d_in, const int* in_sizes, int n_in,
                              void* d_out, int out_size, void* d_ws, size_t ws_size,
                              hipStream_t stream)
{
    const float* means2d = (const float*)d_in[0];   // [1,1024,2]
    const float* conics  = (const float*)d_in[1];   // [1,1024,3]
    const float* colors  = (const float*)d_in[2];   // [1,1024,3]
    const float* opac    = (const float*)d_in[3];   // [1,1024]
    const float* depths  = (const float*)d_in[4];   // [1,1024]

    WS* ws = (WS*)d_ws;  // 44 KB

    setup<<<NG / 64, 64, 0, stream>>>(means2d, conics, colors, opac, depths, ws);
    raster<<<TX * TY, 64, 0, stream>>>(ws, (float*)d_out);
}

// Round 9
// 83.600 us; speedup vs baseline: 3.0590x; 1.2147x over previous
//
#include <hip/hip_runtime.h>

#define IMG_H 192
#define IMG_W 192
#define NG    1024
#define TILE  8            // 8x8 pixel tiles
#define TX    24           // IMG_W / TILE
#define TY    24           // IMG_H / TILE
#define FRONT_K 8
#define ALPHA_THRESH (1.0f / 255.0f)
#define ALPHA_CLAMP  0.999f
#define CAP   64           // candidates staged to LDS per chunk

// ---------------------------------------------------------------------------
// Single fused kernel. 1 block = 1 wave = one 8x8 pixel tile (576 blocks).
//
// Per-pixel validity (alpha >= 1/255) implies the gaussian's conservative
// bbox overlaps the pixel's tile, so the reference's GLOBAL first-K-valid
// truncation and compositing order only require relative depth order within
// this tile's candidate set. Each block therefore:
//   phase 1: tests all 1024 gaussians against its tile (16 per lane),
//            ballot-compacts hits (idx, depth) into LDS;
//   phase 2: rank-sorts the ~18 candidates by (depth, idx) — exact stable
//            argsort order (strict total order, unique ranks);
//   phase 3: chunked LDS gather + front-to-back composite with the exact
//            reference validity test (sigma>=0 && op*exp(-sigma)>=1/255).
// No setup kernel, no global sort, no d_ws use, one launch.
// ---------------------------------------------------------------------------
__global__ __launch_bounds__(64) void raster_fused(
    const float* __restrict__ means2d, const float* __restrict__ conics,
    const float* __restrict__ colors,  const float* __restrict__ opac,
    const float* __restrict__ depths,  float* __restrict__ out)
{
    __shared__ unsigned short cg[NG];   // candidate original index
    __shared__ float          cd[NG];   // candidate depth
    __shared__ unsigned short sg[NG];   // depth-sorted candidate index
    __shared__ float4 gA[CAP];          // mx, my, conic_a, conic_b
    __shared__ float4 gB[CAP];          // conic_c, sigma_thr, opacity, col_r
    __shared__ float2 gC[CAP];          // col_g, col_b

    const int lane = threadIdx.x;
    const int tx = blockIdx.x % TX;
    const int ty = blockIdx.x / TX;

    // tile pixel-center bounds (exact fp: small ints + 0.5)
    const float px0 = (float)(tx * TILE) + 0.5f;
    const float px1 = px0 + (float)(TILE - 1);
    const float py0 = (float)(ty * TILE) + 0.5f;
    const float py1 = py0 + (float)(TILE - 1);

    // --- phase 1: cull all gaussians vs this tile, ballot-compact hits ---
    int n = 0;
    for (int c = 0; c < NG / 64; ++c) {
        const int g = c * 64 + lane;
        const float mx = means2d[2 * g + 0];
        const float my = means2d[2 * g + 1];
        const float ca = conics[3 * g + 0];
        const float cb = conics[3 * g + 1];
        const float cc = conics[3 * g + 2];
        const float op = opac[g];
        // exact alpha test passes only if sigma <= ln(255*op); +1e-3 margin
        // (>> f32 ulps) keeps the pre-filter conservative.
        const float thr = __logf(255.0f * op) + 1e-3f;
        const float det = ca * cc - cb * cb;
        bool hit = false;
        if (thr > 0.0f && det > 0.0f) {
            // conservative ellipse extents: dx^2 <= 2*thr*c/det etc.
            const float hx = sqrtf(2.0f * thr * cc / det) + 0.01f;
            const float hy = sqrtf(2.0f * thr * ca / det) + 0.01f;
            hit = (mx - hx <= px1) && (mx + hx >= px0) &&
                  (my - hy <= py1) && (my + hy >= py0);
        }
        const unsigned long long m = __ballot(hit);
        if (hit) {
            const int pos = n + __popcll(m & ((1ull << lane) - 1ull));
            cg[pos] = (unsigned short)g;
            cd[pos] = depths[g];
        }
        n += __popcll(m);                 // uniform across the wave
    }
    __syncthreads();

    // --- phase 2: rank-sort candidates by (depth, idx) ---
    // rank_r = #{ j : (d_j, g_j) < (d_r, g_r) } — unique ranks, exact
    // stable-argsort relative order (matches jnp.argsort restricted to set).
    for (int r = lane; r < n; r += 64) {
        const float dr = cd[r];
        const int   gr = cg[r];
        int rank = 0;
        for (int j = 0; j < n; ++j) {
            const float dj = cd[j];
            rank += (dj < dr) || (dj == dr && cg[j] < gr);
        }
        sg[rank] = (unsigned short)gr;
    }
    __syncthreads();

    // --- phase 3: chunked LDS gather + front-to-back composite ---
    const int col = lane & 7, row = lane >> 3;
    const float px = px0 + (float)col;    // == (tx*8+col) + 0.5 exactly
    const float py = py0 + (float)row;

    float T = 1.0f, accr = 0.0f, accg = 0.0f, accb = 0.0f;
    int cnt = 0;

    for (int start = 0; start < n; start += CAP) {
        const int m2 = min(CAP, n - start);
        if (lane < m2) {                  // parallel gather, one latency
            const int g = sg[start + lane];
            const float mx = means2d[2 * g + 0];
            const float my = means2d[2 * g + 1];
            const float ca = conics[3 * g + 0];
            const float cb = conics[3 * g + 1];
            const float cc = conics[3 * g + 2];
            const float op = opac[g];
            const float thr = __logf(255.0f * op) + 1e-3f;
            gA[lane] = make_float4(mx, my, ca, cb);
            gB[lane] = make_float4(cc, thr, op, colors[3 * g + 0]);
            gC[lane] = make_float2(colors[3 * g + 1], colors[3 * g + 2]);
        }
        __syncthreads();

        for (int i = 0; i < m2; ++i) {
            const float4 A  = gA[i];      // wave-uniform broadcast
            const float4 Bv = gB[i];
            const float dx = px - A.x;
            const float dy = py - A.y;
            // same op order as reference
            const float sigma = 0.5f * (A.z * dx * dx + Bv.x * dy * dy)
                              + A.w * dx * dy;
            if (sigma >= 0.0f && sigma <= Bv.y && cnt < FRONT_K) {
                float alpha = Bv.z * __expf(-sigma);
                if (alpha >= ALPHA_THRESH) {   // exact reference test
                    alpha = fminf(alpha, ALPHA_CLAMP);
                    const float w = T * alpha;
                    const float2 C = gC[i];
                    accr += w * Bv.w;
                    accg += w * C.x;
                    accb += w * C.y;
                    T *= (1.0f - alpha);
                    ++cnt;
                }
            }
            if ((i & 7) == 7 && __all(cnt >= FRONT_K)) { start = NG; break; }
        }
        __syncthreads();                  // before next chunk rewrite
        if (__all(cnt >= FRONT_K)) break;
    }

    // BG = (0,0,0): no background term.
    const int pix = (ty * TILE + row) * IMG_W + (tx * TILE + col);
    out[pix * 3 + 0] = accr;
    out[pix * 3 + 1] = accg;
    out[pix * 3 + 2] = accb;
}

// ---------------------------------------------------------------------------
extern "C" void kernel_launch(void* const* d_in, const int* in_sizes, int n_in,
                              void* d_out, int out_size, void* d_ws, size_t ws_size,
                              hipStream_t stream)
{
    const float* means2d = (const float*)d_in[0];   // [1,1024,2]
    const float* conics  = (const float*)d_in[1];   // [1,1024,3]
    const float* colors  = (const float*)d_in[2];   // [1,1024,3]
    const float* opac    = (const float*)d_in[3];   // [1,1024]
    const float* depths  = (const float*)d_in[4];   // [1,1024]

    (void)d_ws; (void)ws_size;  // no workspace needed — single fused kernel

    raster_fused<<<TX * TY, 64, 0, stream>>>(
        means2d, conics, colors, opac, depths, (float*)d_out);
}

// Round 11
// 77.122 us; speedup vs baseline: 3.3160x; 1.0840x over previous
//
#include <hip/hip_runtime.h>

#define IMG_H 192
#define IMG_W 192
#define NG    1024
#define TILE  8            // 8x8 pixel tiles, composited per wave
#define QTX   12           // quad-tile grid: one block = 16x16 pixels
#define QTY   12
#define FRONT_K 8
#define ALPHA_THRESH (1.0f / 255.0f)
#define ALPHA_CLAMP  0.999f
#define CAP   64           // candidates staged to LDS per chunk

// ---------------------------------------------------------------------------
// Single fused kernel, v2: 1 block = 256 threads = 4 waves = 16x16 pixels
// (one 8x8 tile per wave). 144 blocks.
//
// vs v1 (576 x 1-wave blocks): 4 waves co-resident per block hide the L2
// latency of the cull loads; cull work per block drops 16 -> 4 gaussians
// per thread (fully unrolled, all loads in flight).
//
// Correctness: the candidate list is a conservative SUPERSET of all
// gaussians that can pass the exact validity test at any pixel of the
// 16x16 region; list order = global depth order restricted to the set
// (rank by (depth, idx) = stable argsort). Non-contributing candidates
// fail the exact per-pixel test (sigma>=0 && op*exp(-sigma)>=1/255) and
// affect neither cnt nor T, so per-pixel FRONT_K truncation and
// compositing match the reference exactly.
// ---------------------------------------------------------------------------
__global__ __launch_bounds__(256) void raster_fused(
    const float* __restrict__ means2d, const float* __restrict__ conics,
    const float* __restrict__ colors,  const float* __restrict__ opac,
    const float* __restrict__ depths,  float* __restrict__ out)
{
    __shared__ unsigned short cg[NG];   // candidate original index
    __shared__ float          cd[NG];   // candidate depth
    __shared__ unsigned short sg[NG];   // depth-sorted candidate index
    __shared__ int            wcnt[4];  // per-wave hit counts (compaction)
    __shared__ float4 gA[CAP];          // mx, my, conic_a, conic_b
    __shared__ float4 gB[CAP];          // conic_c, sigma_thr, opacity, col_r
    __shared__ float2 gC[CAP];          // col_g, col_b

    const int tid  = threadIdx.x;
    const int lane = tid & 63;
    const int wid  = tid >> 6;
    const int qx = blockIdx.x % QTX;
    const int qy = blockIdx.x / QTX;

    // 16x16 region pixel-center bounds (exact fp: small ints + 0.5)
    const float rx0 = (float)(qx * 16) + 0.5f;
    const float rx1 = rx0 + 15.0f;
    const float ry0 = (float)(qy * 16) + 0.5f;
    const float ry1 = ry0 + 15.0f;

    // --- phase 1: cull all gaussians vs region, cross-wave compaction ---
    int n = 0;
    #pragma unroll
    for (int c = 0; c < NG / 256; ++c) {
        const int g = c * 256 + tid;
        const float mx = means2d[2 * g + 0];
        const float my = means2d[2 * g + 1];
        const float ca = conics[3 * g + 0];
        const float cb = conics[3 * g + 1];
        const float cc = conics[3 * g + 2];
        const float op = opac[g];
        const float dp = depths[g];            // in flight with the rest
        // exact alpha test passes only if sigma <= ln(255*op); +1e-3 margin
        // (>> f32 ulps) keeps the pre-filter conservative.
        const float thr = __logf(255.0f * op) + 1e-3f;
        const float det = ca * cc - cb * cb;   // inputs are PD: det > 0
        bool hit = false;
        if (thr > 0.0f && det > 0.0f) {
            // conservative ellipse extents: dx^2 <= 2*thr*c/det etc.
            const float hx = sqrtf(2.0f * thr * cc / det) + 0.01f;
            const float hy = sqrtf(2.0f * thr * ca / det) + 0.01f;
            hit = (mx - hx <= rx1) && (mx + hx >= rx0) &&
                  (my - hy <= ry1) && (my + hy >= ry0);
        }
        const unsigned long long m = __ballot(hit);
        if (lane == 0) wcnt[wid] = __popcll(m);
        __syncthreads();
        int ofs = n;
        #pragma unroll
        for (int w = 0; w < 4; ++w) {          // prefix over earlier waves
            if (w < wid) ofs += wcnt[w];
        }
        const int tot = wcnt[0] + wcnt[1] + wcnt[2] + wcnt[3];
        if (hit) {
            const int pos = ofs + __popcll(m & ((1ull << lane) - 1ull));
            cg[pos] = (unsigned short)g;
            cd[pos] = dp;
        }
        n += tot;
        __syncthreads();                       // wcnt reused next chunk
    }

    // --- phase 2: rank-sort candidates by (depth, idx) ---
    // rank_r = #{ j : (d_j, g_j) < (d_r, g_r) } — unique ranks, exact
    // stable-argsort relative order.
    for (int r = tid; r < n; r += 256) {
        const float dr = cd[r];
        const int   gr = cg[r];
        int rank = 0;
        for (int j = 0; j < n; ++j) {
            const float dj = cd[j];
            rank += (dj < dr) || (dj == dr && cg[j] < gr);
        }
        sg[rank] = (unsigned short)gr;
    }
    __syncthreads();

    // --- phase 3: chunked LDS gather + per-wave front-to-back composite ---
    const int tx = qx * 2 + (wid & 1);         // this wave's 8x8 tile
    const int ty = qy * 2 + (wid >> 1);
    const int col = lane & 7, row = lane >> 3;
    const float px = (float)(tx * TILE + col) + 0.5f;
    const float py = (float)(ty * TILE + row) + 0.5f;

    float T = 1.0f, accr = 0.0f, accg = 0.0f, accb = 0.0f;
    int cnt = 0;

    for (int start = 0; start < n; start += CAP) {
        const int m2 = min(CAP, n - start);
        if (tid < m2) {                        // parallel gather, one latency
            const int g = sg[start + tid];
            const float mx = means2d[2 * g + 0];
            const float my = means2d[2 * g + 1];
            const float ca = conics[3 * g + 0];
            const float cb = conics[3 * g + 1];
            const float cc = conics[3 * g + 2];
            const float op = opac[g];
            const float thr = __logf(255.0f * op) + 1e-3f;
            gA[tid] = make_float4(mx, my, ca, cb);
            gB[tid] = make_float4(cc, thr, op, colors[3 * g + 0]);
            gC[tid] = make_float2(colors[3 * g + 1], colors[3 * g + 2]);
        }
        __syncthreads();

        if (!__all(cnt >= FRONT_K)) {          // wave-level skip, no barrier
            for (int i = 0; i < m2; ++i) {
                const float4 A  = gA[i];       // wave-uniform broadcast
                const float4 Bv = gB[i];
                const float dx = px - A.x;
                const float dy = py - A.y;
                // same op order as reference
                const float sigma = 0.5f * (A.z * dx * dx + Bv.x * dy * dy)
                                  + A.w * dx * dy;
                if (sigma >= 0.0f && sigma <= Bv.y && cnt < FRONT_K) {
                    float alpha = Bv.z * __expf(-sigma);
                    if (alpha >= ALPHA_THRESH) {   // exact reference test
                        alpha = fminf(alpha, ALPHA_CLAMP);
                        const float w = T * alpha;
                        const float2 C = gC[i];
                        accr += w * Bv.w;
                        accg += w * C.x;
                        accb += w * C.y;
                        T *= (1.0f - alpha);
                        ++cnt;
                    }
                }
            }
        }
        // block-uniform barrier + early exit (protects gA rewrite too)
        if (__syncthreads_and(cnt >= FRONT_K)) break;
    }

    // BG = (0,0,0): no background term.
    const int pix = (ty * TILE + row) * IMG_W + (tx * TILE + col);
    out[pix * 3 + 0] = accr;
    out[pix * 3 + 1] = accg;
    out[pix * 3 + 2] = accb;
}

// ---------------------------------------------------------------------------
extern "C" void kernel_launch(void* const* d_in, const int* in_sizes, int n_in,
                              void* d_out, int out_size, void* d_ws, size_t ws_size,
                              hipStream_t stream)
{
    const float* means2d = (const float*)d_in[0];   // [1,1024,2]
    const float* conics  = (const float*)d_in[1];   // [1,1024,3]
    const float* colors  = (const float*)d_in[2];   // [1,1024,3]
    const float* opac    = (const float*)d_in[3];   // [1,1024]
    const float* depths  = (const float*)d_in[4];   // [1,1024]

    (void)d_ws; (void)ws_size;  // no workspace needed — single fused kernel

    raster_fused<<<QTX * QTY, 256, 0, stream>>>(
        means2d, conics, colors, opac, depths, (float*)d_out);
}